// Round 3
// baseline (99.688 us; speedup 1.0000x reference)
//
#include <hip/hip_runtime.h>

// QuantumDMRGLayer: B=2048, L=196, M=16, NBL=10, pos_label=98 (fixed by setup).
// Round-10: v9 (fused) was VALU-issue-bound at ~40us with ~2.5x overhead above
// the basis-decomposition's intrinsic floor (~17us): per-wave global G streams
// (8 different segments per block -> 200MB L2 traffic, per-site prefetch ring)
// and ~130 live VGPRs under a 128 cap. v10 strips to the floor:
//   - seg_kernel: block = 32 samples x ONE segment (16 waves, 1024 thr).
//     G slice (<=50KB) + X slab staged to LDS ONCE, then a barrier-free chain
//     loop: per wave-site 2x ds_read_b128 + 3 MFMA + combine/repack. Lean
//     state (~80 VGPR) -> 4 waves/SIMD real occupancy. 512 blocks = 2 clean
//     rounds over 256 CUs.
//   - S (16.8MB) round-trips global, but comb_kernel is depth-4 (not 98):
//     all 4 segment matrices preloaded to registers, 16-lane shfl applies,
//     fused T contraction. ~2us.
// Per-site math, segment boundaries, combine order: verbatim from passing v9.

typedef __attribute__((ext_vector_type(8))) short short8;
typedef __attribute__((ext_vector_type(16))) float floatx16;

#define GSITE_DW 512                 // dwords per site (hi 256 | lo 256)
#define GDIR_DW (100 * GSITE_DW)     // 100 sites per dir (2 pad)
#define S_OFF_DW (2 * GDIR_DW)       // float offset of S in d_ws (400 KB)
// S: [8 segs][2048 samples][16 out][16 in] floats = 16.8 MB

__device__ __forceinline__ unsigned bf16_rne(unsigned u) {
    return (u + 0x7FFFu + ((u >> 16) & 1u)) >> 16;
}

// ---- prep: build split-bf16, row-permuted G streams in d_ws (unchanged) ----
// lane l holds A-operand row r=l&31, k = 8*(l>>5)+j.  Stored value =
// G[pi(r), k],  pi = swap bits 2<->3 of low nibble (keeps bit4 = d).
//   left  (site p):    G[(d,nn),k] = AM[p,      d, k, nn]   (v <- v @ W)
//   right (site 193-p):G[(d,nn),k] = AM[193-p,  d, nn, k]   (v <- W @ v)
__global__ __launch_bounds__(256)
void prep_kernel(const float* __restrict__ AM, unsigned* __restrict__ WS)
{
    int t = blockIdx.x * 256 + threadIdx.x;    // < 51200
    const int w    = t & 3;  t >>= 2;          // dword index 0..3
    const int lane = t & 63; t >>= 6;
    const int p    = t % 100;
    const int dir  = t / 100;
    const int kb = (lane >> 5) << 3;
    const int r  = lane & 31;
    const int rr = (r & 0x13) | ((r & 4) << 1) | ((r & 8) >> 1);  // pi(r)
    const int d = rr >> 4, nn = rr & 15;
    const int lim = dir ? 96 : 98;
    const int a = dir ? (193 - p) : p;
    const int k0 = kb + 2 * w;
    float g0 = 0.f, g1 = 0.f;
    if (p < lim) {
        const float* Ab = AM + a * 512 + d * 256;
        if (dir == 0) { g0 = Ab[k0 * 16 + nn]; g1 = Ab[(k0 + 1) * 16 + nn]; }
        else          { g0 = Ab[nn * 16 + k0]; g1 = Ab[nn * 16 + k0 + 1]; }
    }
    const unsigned u0 = __float_as_uint(g0), u1 = __float_as_uint(g1);
    const unsigned h0 = bf16_rne(u0), h1 = bf16_rne(u1);
    const float l0f = g0 - __uint_as_float(h0 << 16);
    const float l1f = g1 - __uint_as_float(h1 << 16);
    const unsigned lo0 = bf16_rne(__float_as_uint(l0f));
    const unsigned lo1 = bf16_rne(__float_as_uint(l1f));
    unsigned* gp = WS + (dir * 100 + p) * GSITE_DW;
    gp[lane * 4 + w]       = (h1 << 16) | h0;
    gp[256 + lane * 4 + w] = (lo1 << 16) | lo0;
}

// ---- stage 1: segment products, one segment per block, G in LDS ----
// block b: seg = b&7 (dir = seg>>2, si = seg&3), samples sb = (b>>3)*32.
// wave wv (0..15): 32 cols = 2 samples (sb+2wv, sb+2wv+1) x 16 basis.
//   dir0 seg [p0,p1): col m = e_m^T W_p0..W_{p1-1}  -> S = P^T
//   dir1 seg [p0,p1): col m = W_{193-(p1-1)}..W_{193-p0} e_m -> S = Q
// Store S[seg][s][out k][in m]: apply is v'[n] = sum_m S[n][m] v[m].
__global__ __launch_bounds__(1024, 4)
void seg_kernel(const float* __restrict__ X,
                const unsigned* __restrict__ WS,
                float* __restrict__ S)
{
    __shared__ unsigned sG[25 * GSITE_DW];     // 51.2 KB
    __shared__ float2 sxv[32][25];             // 6.4 KB

    const int tid  = threadIdx.x;
    const int lane = tid & 63;
    const int wv   = tid >> 6;                 // 0..15
    const int seg  = blockIdx.x & 7;
    const int sb   = (blockIdx.x >> 3) * 32;
    const int dir  = seg >> 2;
    const int si   = seg & 3;
    int p0, p1;
    if (dir == 0) { p0 = (si < 2) ? 25 * si : 50 + 24 * (si - 2);
                    p1 = p0 + ((si < 2) ? 25 : 24); }
    else          { p0 = 24 * si; p1 = p0 + 24; }
    const int len = p1 - p0;

    // ---- phase 1: stage G slice + x slab ----
    const int4* gsrc = (const int4*)(WS + (dir * 100 + p0) * GSITE_DW);
    const int n4 = len * 128;
    for (int i = tid; i < n4; i += 1024)
        ((int4*)sG)[i] = gsrc[i];
    for (int i = tid; i < 32 * 25; i += 1024) {
        const int smp = i / 25, li = i - smp * 25;
        if (li < len) {
            const int p = p0 + li;
            const int xo = dir ? (388 - 2 * p) : (2 + 2 * p);
            sxv[smp][li] = *(const float2*)(X + (sb + smp) * 392 + xo);
        }
    }
    __syncthreads();

    const int sel = (lane >> 4) & 1;           // sample within pair
    const int m   = lane & 15;                 // basis index (column)
    const int kb  = (lane >> 5) << 3;          // this lane's k-half base
    const int s   = sb + 2 * wv + sel;

    // ---- init basis e_m: hi = bf16(exact), lo = 0 ----
    int4 vh, vl;
#pragma unroll
    for (int q = 0; q < 4; ++q) {
        unsigned hw = 0;
        if (kb + 2 * q == m)     hw |= 0x3F80u;
        if (kb + 2 * q + 1 == m) hw |= 0x3F800000u;
        ((unsigned*)&vh)[q] = hw;
        ((unsigned*)&vl)[q] = 0;
    }

    // ---- chain loop (1-ahead LDS prefetch) ----
    const unsigned* Gl = sG + lane * 4;
    int4 GHc = *(const int4*)(Gl);
    int4 GLc = *(const int4*)(Gl + 256);
    float2 xc = sxv[2 * wv + sel][0];
    float w[8];
    for (int q = 0; q < len; ++q) {
        const int qn = (q + 1 < len) ? q + 1 : q;
        const int4 GHn = *(const int4*)(Gl + qn * GSITE_DW);
        const int4 GLn = *(const int4*)(Gl + qn * GSITE_DW + 256);
        const float2 xn = sxv[2 * wv + sel][qn];

        const short8 ah = *(const short8*)&GHc;
        const short8 al = *(const short8*)&GLc;
        const short8 bh = *(const short8*)&vh;
        const short8 bl = *(const short8*)&vl;
        floatx16 D = {};
        D = __builtin_amdgcn_mfma_f32_32x32x16_bf16(ah, bh, D, 0, 0, 0);
        D = __builtin_amdgcn_mfma_f32_32x32x16_bf16(ah, bl, D, 0, 0, 0);
        D = __builtin_amdgcn_mfma_f32_32x32x16_bf16(al, bh, D, 0, 0, 0);
#pragma unroll
        for (int j = 0; j < 8; ++j)            // D[j]=W0, D[j+8]=W1, k=kb+j
            w[j] = fmaf(xc.x, D[j], xc.y * D[j + 8]);
        if (q + 1 < len) {                     // repack (skip on last site)
#pragma unroll
            for (int qq = 0; qq < 4; ++qq) {
                const unsigned u0 = __float_as_uint(w[2 * qq]);
                const unsigned u1 = __float_as_uint(w[2 * qq + 1]);
                const float l0 = w[2 * qq]     - __uint_as_float(u0 & 0xFFFF0000u);
                const float l1 = w[2 * qq + 1] - __uint_as_float(u1 & 0xFFFF0000u);
                ((unsigned*)&vh)[qq] = __builtin_amdgcn_perm(u1, u0, 0x07060302u);
                ((unsigned*)&vl)[qq] = __builtin_amdgcn_perm(
                    __float_as_uint(l1), __float_as_uint(l0), 0x07060302u);
            }
        }
        GHc = GHn; GLc = GLn; xc = xn;
    }

    // ---- store segment product S[seg][s][k][m] ----
    float* Sp = S + ((seg * 2048 + s) << 8) + m;
#pragma unroll
    for (int j = 0; j < 8; ++j)
        Sp[(kb + j) << 4] = w[j];
}

// ---- stage 2: depth-4 combine + T contraction ----
// block = 8 samples x 2 chains x 16 components (256 thr). All 4 segment
// matrices preloaded to registers; 4 applies of 16 shfl+fma; T at the end.
__global__ __launch_bounds__(256)
void comb_kernel(const float* __restrict__ X,
                 const float* __restrict__ AL,
                 const float* __restrict__ AR,
                 const float* __restrict__ T,
                 const float* __restrict__ S,
                 float* __restrict__ OUT)
{
    __shared__ float sT[2560];
    __shared__ float sv[8][2][16];
    const int tid = threadIdx.x;
    for (int k = tid; k < 640; k += 256)
        ((float4*)sT)[k] = ((const float4*)T)[k];

    const int g     = tid >> 4;                // 0..15
    const int n     = tid & 15;
    const int smp   = g >> 1;
    const int chain = g & 1;                   // 0 = left, 1 = right
    const int s     = blockIdx.x * 8 + smp;

    float4 r[4][4];                            // [seg q][quarter]
#pragma unroll
    for (int q = 0; q < 4; ++q) {
        const float4* Ps =
            (const float4*)(S + (((chain * 4 + q) * 2048 + s) << 8) + (n << 4));
        r[q][0] = Ps[0]; r[q][1] = Ps[1]; r[q][2] = Ps[2]; r[q][3] = Ps[3];
    }
    const float2 x = *(const float2*)(X + s * 392 + (chain ? 390 : 0));
    const float* Ab = chain ? AR : AL;
    float v = x.x * Ab[n] + x.y * Ab[16 + n];
#pragma unroll
    for (int q = 0; q < 4; ++q) {
        float acc = 0.f;
#pragma unroll
        for (int mm = 0; mm < 16; ++mm)
            acc = fmaf(((const float*)&r[q][mm >> 2])[mm & 3],
                       __shfl(v, mm, 16), acc);
        v = acc;
    }
    sv[smp][chain][n] = v;
    __syncthreads();

    if (tid < 80) {
        const int s2 = tid / 10, l = tid - s2 * 10;
        const float* Lp = sv[s2][0];
        const float* Rp = sv[s2][1];
        float acc = 0.f;
#pragma unroll
        for (int mm = 0; mm < 16; ++mm) {
            const float lm = Lp[mm];
            const float* Tp = sT + mm * 160 + l;
#pragma unroll
            for (int nn = 0; nn < 16; ++nn)
                acc = fmaf(lm * Rp[nn], Tp[nn * 10], acc);
        }
        OUT[(blockIdx.x * 8 + s2) * 10 + l] = acc;
    }
}

extern "C" void kernel_launch(void* const* d_in, const int* in_sizes, int n_in,
                              void* d_out, int out_size, void* d_ws, size_t ws_size,
                              hipStream_t stream)
{
    const float* X  = (const float*)d_in[0];   // (2048,196,2)
    const float* AL = (const float*)d_in[1];   // (2,16)
    const float* AM = (const float*)d_in[2];   // (194,2,16,16)
    const float* AR = (const float*)d_in[3];   // (2,16)
    const float* T  = (const float*)d_in[4];   // (16,16,10)
    (void)in_sizes; (void)n_in; (void)out_size; (void)ws_size;
    unsigned* WS = (unsigned*)d_ws;            // G streams: 400 KB
    float* S     = (float*)d_ws + S_OFF_DW;    // segment products: 16.8 MB
    float* OUT   = (float*)d_out;              // (2048,10)

    hipLaunchKernelGGL(prep_kernel, dim3(200), dim3(256),  0, stream, AM, WS);
    hipLaunchKernelGGL(seg_kernel,  dim3(512), dim3(1024), 0, stream, X, WS, S);
    hipLaunchKernelGGL(comb_kernel, dim3(256), dim3(256),  0, stream,
                       X, AL, AR, T, S, OUT);
}